// Round 2
// baseline (540.012 us; speedup 1.0000x reference)
//
#include <hip/hip_runtime.h>
#include <hip/hip_bf16.h>
#include <math.h>

#define N_NODES 20000
#define N_EDGES 640000
#define ET_EDGES (N_EDGES + N_NODES)   // with self-loops
#define G_GRAPHS 64
#define NEG_SLOPE 0.2f

// ---------------- CSR construction (+ graph bounds folded in) ----------------

__global__ void hist_dst(const int* __restrict__ ei, int* __restrict__ cnt,
                         const int* __restrict__ batch, int* __restrict__ gstart) {
    int j = blockIdx.x * blockDim.x + threadIdx.x;
    if (blockIdx.x == 0 && threadIdx.x <= G_GRAPHS) {
        int g = threadIdx.x;
        int lo = 0, hi = N_NODES;
        while (lo < hi) {              // first i with batch[i] >= g
            int mid = (lo + hi) >> 1;
            if (batch[mid] < g) lo = mid + 1; else hi = mid;
        }
        gstart[g] = lo;
    }
    if (j >= ET_EDGES) return;
    int d = (j < N_EDGES) ? ei[N_EDGES + j] : (j - N_EDGES);
    atomicAdd(&cnt[d], 1);
}

__global__ __launch_bounds__(1024) void scan_rowptr(const int* __restrict__ cnt,
                                                    int* __restrict__ row_ptr) {
    __shared__ int sums[1024];
    const int n = N_NODES;
    const int CH = (n + 1023) / 1024;   // 20
    int t = threadIdx.x;
    int base = t * CH;
    int s = 0;
    for (int i = 0; i < CH; ++i) {
        int idx = base + i;
        if (idx < n) s += cnt[idx];
    }
    sums[t] = s;
    __syncthreads();
    for (int o = 1; o < 1024; o <<= 1) {
        int v = (t >= o) ? sums[t - o] : 0;
        __syncthreads();
        sums[t] += v;
        __syncthreads();
    }
    int run = (t == 0) ? 0 : sums[t - 1];
    for (int i = 0; i < CH; ++i) {
        int idx = base + i;
        if (idx < n) { row_ptr[idx] = run; run += cnt[idx]; }
    }
    if (t == 1023) row_ptr[n] = sums[1023];
}

// colb stores PRE-SCALED byte offsets: s << 10 (= s * 256ch * 4B).
// Consumers shift: aggregate F=256 uses as-is, F=128 uses >>1,
// edge_alpha H=4 ([N][4] f32 table) uses >>6, H=1 uses >>8.
__global__ void fill_csr(const int* __restrict__ ei, const int* __restrict__ row_ptr,
                         int* __restrict__ cur, int* __restrict__ colb) {
    int j = blockIdx.x * blockDim.x + threadIdx.x;
    if (j >= ET_EDGES) return;
    int s, d;
    if (j < N_EDGES) { s = ei[j]; d = ei[N_EDGES + j]; }
    else             { s = d = j - N_EDGES; }
    int pos = row_ptr[d] + atomicAdd(&cur[d], 1);
    colb[pos] = s << 10;
}

// ---------------- fp32 SGEMM: C[M,Nc] = A[M,K] @ B[K,Nc] ----------------

__global__ __launch_bounds__(256) void sgemm64(const float* __restrict__ A,
                                               const float* __restrict__ B,
                                               float* __restrict__ C,
                                               int M, int K, int Nc) {
    __shared__ float As[16][64];
    __shared__ float Bs[16][64];
    int bm = blockIdx.x * 64;
    int bn = blockIdx.y * 64;
    int t = threadIdx.x;
    int tr = t >> 2, tq = t & 3;
    int bkr = t >> 4, bnq = t & 15;
    int tm = (t >> 4) * 4;
    int tn = (t & 15) * 4;
    float acc[4][4] = {};
    for (int k0 = 0; k0 < K; k0 += 16) {
        int ar = bm + tr;
        float4 av = make_float4(0.f, 0.f, 0.f, 0.f);
        if (ar < M) av = *(const float4*)&A[(size_t)ar * K + k0 + tq * 4];
        As[tq * 4 + 0][tr] = av.x;
        As[tq * 4 + 1][tr] = av.y;
        As[tq * 4 + 2][tr] = av.z;
        As[tq * 4 + 3][tr] = av.w;
        float4 bv = *(const float4*)&B[(size_t)(k0 + bkr) * Nc + bn + bnq * 4];
        *(float4*)&Bs[bkr][bnq * 4] = bv;
        __syncthreads();
        #pragma unroll
        for (int k = 0; k < 16; ++k) {
            float a[4], b[4];
            *(float4*)a = *(const float4*)&As[k][tm];
            *(float4*)b = *(const float4*)&Bs[k][tn];
            #pragma unroll
            for (int i = 0; i < 4; ++i)
                #pragma unroll
                for (int j = 0; j < 4; ++j)
                    acc[i][j] = fmaf(a[i], b[j], acc[i][j]);
        }
        __syncthreads();
    }
    #pragma unroll
    for (int i = 0; i < 4; ++i) {
        int r = bm + tm + i;
        if (r < M) {
            float4 o = make_float4(acc[i][0], acc[i][1], acc[i][2], acc[i][3]);
            *(float4*)&C[(size_t)r * Nc + bn + tn] = o;
        }
    }
}

// ---------------- per-node attention coefficients (interleaved [N][H]) ------

template <int HEADS, int C>
__global__ __launch_bounds__(256) void node_alpha3(const float* __restrict__ h,
                                                   const float* __restrict__ a_src,
                                                   const float* __restrict__ a_dst,
                                                   float* __restrict__ asi,   // [N][H]
                                                   float* __restrict__ adi) { // [N][H]
    constexpr int F = HEADS * C;
    constexpr int VEC = F / 64;        // 4 (F=256) or 2 (F=128)
    constexpr int LPH = C / VEC;       // lanes per head: 16 or 64
    int wid = threadIdx.x >> 6, lane = threadIdx.x & 63;
    int v = blockIdx.x * 4 + wid;
    if (v >= N_NODES) return;
    const float* hp = h + (size_t)v * F + lane * VEC;
    float ps = 0.f, pd = 0.f;
    #pragma unroll
    for (int c = 0; c < VEC; ++c) {
        float hv = hp[c];
        ps = fmaf(hv, a_src[lane * VEC + c], ps);
        pd = fmaf(hv, a_dst[lane * VEC + c], pd);
    }
    #pragma unroll
    for (int o = LPH / 2; o; o >>= 1) {
        ps += __shfl_xor(ps, o);
        pd += __shfl_xor(pd, o);
    }
    if ((lane & (LPH - 1)) == 0) {
        int head = lane / LPH;
        asi[v * HEADS + head] = ps;
        adi[v * HEADS + head] = pd;
    }
}

// ---------------- per-edge attention weights (unnormalized) -----------------
// One wave per dst node; lane = (edge k, head h). Writes p[e][H] (coalesced)
// and the per-node softmax denominator dn[v][H]. Aggregate divides at the end
// (identical numerics: sum(p*h)/dn == sum((p/dn)*h)).

template <int H>
__global__ __launch_bounds__(256) void edge_alpha(
        const float* __restrict__ asi,    // [N][H]
        const float* __restrict__ adi,    // [N][H]
        const int* __restrict__ row_ptr,
        const int* __restrict__ colb,     // byte offsets s<<10
        float* __restrict__ p,            // [ET][H]
        float* __restrict__ dn) {         // [N][H]
    constexpr int KE = 64 / H;            // edges per pass: 16 (H=4) or 64 (H=1)
    constexpr int SHIFT = (H == 4) ? 6 : 8;  // colb>>SHIFT = byte off into [N][H] f32
    int wid = threadIdx.x >> 6, lane = threadIdx.x & 63;
    int v = blockIdx.x * 4 + wid;
    if (v >= N_NODES) return;
    int k = lane / H, h = lane % H;
    int r0 = row_ptr[v], r1 = row_ptr[v + 1];
    float ad = adi[v * H + h];
    const char* ab = (const char*)asi + h * 4;
    float dsum = 0.f;
    for (int base = r0; base < r1; base += KE) {
        int j = base + k;
        bool valid = j < r1;
        int cb = colb[valid ? j : r0];
        float as = *(const float*)(ab + (cb >> SHIFT));
        float e = as + ad;
        e = (e > 0.f) ? e : NEG_SLOPE * e;
        float pe = __expf(e);
        if (valid) {
            dsum += pe;
            p[(size_t)j * H + h] = pe;
        }
    }
    #pragma unroll
    for (int o = H; o < 64; o <<= 1) dsum += __shfl_xor(dsum, o);
    if (k == 0) dn[v * H + h] = dsum;
}

// ---------------- channel-sliced weighted-gather aggregate ------------------
// Wave = (dst node, channel slice). NSLICE=8: slice = blockIdx.x & 7 -> with
// round-robin dispatch, slice s pins to XCD s; per-XCD h working set =
// N*SCH*4B = 2.5 MB (layers 1/2) -> fits the 4 MB per-XCD L2.
// Pure SpMM: per group, broadcast colb/p loads + one 16B/lane row gather +
// 4 FMA. No LDS, no softmax work (precomputed by edge_alpha).
// SHIFT rescales colb byte offsets for the h row stride (0: F=256, 1: F=128).

template <int NSLICE, int SCH, int F, int H, int SHIFT, bool DO_ELU>
__global__ __launch_bounds__(256) void gat_aggregate3(
        const float* __restrict__ h,      // [N][F]
        const float* __restrict__ p,      // [ET][H] unnormalized
        const float* __restrict__ dn,     // [N][H]
        const int* __restrict__ row_ptr,
        const int* __restrict__ colb,     // byte offsets s<<10
        const float* __restrict__ bias,   // [F]
        float* __restrict__ out) {        // [N][F]
    constexpr int CL = SCH / 4;           // lanes per edge (8 or 4)
    constexpr int E  = 64 / CL;           // parallel edges (8 or 16)
    constexpr int CPH = F / H;            // channels per head
    int slice = blockIdx.x & (NSLICE - 1);
    int ng = blockIdx.x / NSLICE;
    int wid = threadIdx.x >> 6, lane = threadIdx.x & 63;
    int v = ng * 4 + wid;
    if (v >= N_NODES) return;
    int head = (slice * SCH) / CPH;
    int eg = lane / CL, cl = lane % CL;
    int r0 = row_ptr[v], r1 = row_ptr[v + 1];
    const char* hb = (const char*)(h + slice * SCH + cl * 4);
    const float* pp = p + head;           // pp[e*H] = p[e][head]
    float acc[4] = {};

    int e0 = r0;
    // full blocks: 4 groups of E edges, no bounds checks
    for (; e0 + E * 4 <= r1; e0 += E * 4) {
        int ea = e0 + eg, eb = ea + E, ec = eb + E, ed = ec + E;
        int oa = colb[ea] >> SHIFT;
        int ob = colb[eb] >> SHIFT;
        int oc = colb[ec] >> SHIFT;
        int od = colb[ed] >> SHIFT;
        float pa = pp[(size_t)ea * H];
        float pb = pp[(size_t)eb * H];
        float pc = pp[(size_t)ec * H];
        float pd = pp[(size_t)ed * H];
        float4 ha = *(const float4*)(hb + oa);
        float4 hc0 = *(const float4*)(hb + ob);
        float4 hc1 = *(const float4*)(hb + oc);
        float4 hc2 = *(const float4*)(hb + od);
        acc[0] = fmaf(pa, ha.x, acc[0]);
        acc[1] = fmaf(pa, ha.y, acc[1]);
        acc[2] = fmaf(pa, ha.z, acc[2]);
        acc[3] = fmaf(pa, ha.w, acc[3]);
        acc[0] = fmaf(pb, hc0.x, acc[0]);
        acc[1] = fmaf(pb, hc0.y, acc[1]);
        acc[2] = fmaf(pb, hc0.z, acc[2]);
        acc[3] = fmaf(pb, hc0.w, acc[3]);
        acc[0] = fmaf(pc, hc1.x, acc[0]);
        acc[1] = fmaf(pc, hc1.y, acc[1]);
        acc[2] = fmaf(pc, hc1.z, acc[2]);
        acc[3] = fmaf(pc, hc1.w, acc[3]);
        acc[0] = fmaf(pd, hc2.x, acc[0]);
        acc[1] = fmaf(pd, hc2.y, acc[1]);
        acc[2] = fmaf(pd, hc2.z, acc[2]);
        acc[3] = fmaf(pd, hc2.w, acc[3]);
    }
    // remainder: clamped single groups
    for (; e0 < r1; e0 += E) {
        int e = e0 + eg;
        bool valid = e < r1;
        int ee = valid ? e : r0;
        int oa = colb[ee] >> SHIFT;
        float pa = pp[(size_t)ee * H];
        if (!valid) pa = 0.f;
        float4 ha = *(const float4*)(hb + oa);
        acc[0] = fmaf(pa, ha.x, acc[0]);
        acc[1] = fmaf(pa, ha.y, acc[1]);
        acc[2] = fmaf(pa, ha.z, acc[2]);
        acc[3] = fmaf(pa, ha.w, acc[3]);
    }

    // reduce acc across edge groups
    #pragma unroll
    for (int c = 0; c < 4; ++c) {
        #pragma unroll
        for (int o = CL; o < 64; o <<= 1) acc[c] += __shfl_xor(acc[c], o);
    }
    if (eg == 0) {
        float inv = 1.f / (dn[v * H + head] + 1e-16f);
        int ch = slice * SCH + cl * 4;
        float4 o;
        o.x = acc[0] * inv + bias[ch + 0];
        o.y = acc[1] * inv + bias[ch + 1];
        o.z = acc[2] * inv + bias[ch + 2];
        o.w = acc[3] * inv + bias[ch + 3];
        if (DO_ELU) {
            o.x = (o.x > 0.f) ? o.x : expm1f(o.x);
            o.y = (o.y > 0.f) ? o.y : expm1f(o.y);
            o.z = (o.z > 0.f) ? o.z : expm1f(o.z);
            o.w = (o.w > 0.f) ? o.w : expm1f(o.w);
        }
        *(float4*)&out[(size_t)v * F + ch] = o;
    }
}

// ---------------- global mean pool: 4-way row-split + atomic combine --------

__global__ void pool_mean4(const float* __restrict__ hout, const int* __restrict__ gstart,
                           float* __restrict__ gout) {
    int g = blockIdx.x;       // 64
    int q = blockIdx.y;       // 4 row-quarters
    int c = threadIdx.x;      // 128 channels
    int off = gstart[g], end = gstart[g + 1];
    float inv = 1.f / fmaxf((float)(end - off), 1.0f);
    float s = 0.f;
    for (int i = off + q; i < end; i += 4) s += hout[(size_t)i * 128 + c];
    atomicAdd(&gout[g * 128 + c], s * inv);
}

// ---------------- launch ----------------

static inline size_t align_up(size_t x, size_t a) { return (x + a - 1) & ~(a - 1); }

extern "C" void kernel_launch(void* const* d_in, const int* in_sizes, int n_in,
                              void* d_out, int out_size, void* d_ws, size_t ws_size,
                              hipStream_t stream) {
    const float* x   = (const float*)d_in[0];
    const int*   ei  = (const int*)d_in[1];
    const int*   bat = (const int*)d_in[2];
    const float* W1  = (const float*)d_in[3];
    const float* as1 = (const float*)d_in[4];
    const float* ad1 = (const float*)d_in[5];
    const float* b1  = (const float*)d_in[6];
    const float* W2  = (const float*)d_in[7];
    const float* as2 = (const float*)d_in[8];
    const float* ad2 = (const float*)d_in[9];
    const float* b2  = (const float*)d_in[10];
    const float* W3  = (const float*)d_in[11];
    const float* as3 = (const float*)d_in[12];
    const float* ad3 = (const float*)d_in[13];
    const float* b3  = (const float*)d_in[14];

    float* gout = (float*)d_out;                     // [G,128]
    float* hout = (float*)d_out + G_GRAPHS * 128;    // [N,128]

    char* w = (char*)d_ws;
    size_t o = 0;
    float* bufA = (float*)(w + o); o = align_up(o + (size_t)N_NODES * 256 * 4, 256);
    float* bufB = (float*)(w + o); o = align_up(o + (size_t)N_NODES * 256 * 4, 256);
    float* asv  = (float*)(w + o); o = align_up(o + (size_t)N_NODES * 4 * 4, 256);
    float* adv  = (float*)(w + o); o = align_up(o + (size_t)N_NODES * 4 * 4, 256);
    float* pbuf = (float*)(w + o); o = align_up(o + (size_t)ET_EDGES * 4 * 4, 256);
    float* dnv  = (float*)(w + o); o = align_up(o + (size_t)N_NODES * 4 * 4, 256);
    int* row_ptr = (int*)(w + o);  o = align_up(o + (size_t)(N_NODES + 1) * 4, 256);
    int* colb    = (int*)(w + o);  o = align_up(o + (size_t)ET_EDGES * 4, 256);
    int* cnt     = (int*)(w + o);  o += (size_t)N_NODES * 4;        // cnt+cur contiguous
    int* cur     = (int*)(w + o);  o = align_up(o + (size_t)N_NODES * 4, 256);
    int* gstart  = (int*)(w + o);  o = align_up(o + (size_t)(G_GRAPHS + 1) * 4, 256);

    // ---- CSR build + graph bounds ----
    hipMemsetAsync(cnt, 0, (size_t)N_NODES * 8, stream);   // cnt AND cur
    hipMemsetAsync(gout, 0, (size_t)G_GRAPHS * 128 * 4, stream);
    hist_dst<<<(ET_EDGES + 255) / 256, 256, 0, stream>>>(ei, cnt, bat, gstart);
    scan_rowptr<<<1, 1024, 0, stream>>>(cnt, row_ptr);
    fill_csr<<<(ET_EDGES + 255) / 256, 256, 0, stream>>>(ei, row_ptr, cur, colb);

    dim3 g4(313, 4), g2(313, 2);
    int nb = (N_NODES + 3) / 4;   // 4 nodes per block (5000)
    int nbs = nb * 8;             // x8 channel slices

    // ---- layer 1: 128 -> 4x64 ----
    sgemm64<<<g4, 256, 0, stream>>>(x, W1, bufA, N_NODES, 128, 256);
    node_alpha3<4, 64><<<nb, 256, 0, stream>>>(bufA, as1, ad1, asv, adv);
    edge_alpha<4><<<nb, 256, 0, stream>>>(asv, adv, row_ptr, colb, pbuf, dnv);
    gat_aggregate3<8, 32, 256, 4, 0, true><<<nbs, 256, 0, stream>>>(
        bufA, pbuf, dnv, row_ptr, colb, b1, bufB);

    // ---- layer 2: 256 -> 4x64 ----
    sgemm64<<<g4, 256, 0, stream>>>(bufB, W2, bufA, N_NODES, 256, 256);
    node_alpha3<4, 64><<<nb, 256, 0, stream>>>(bufA, as2, ad2, asv, adv);
    edge_alpha<4><<<nb, 256, 0, stream>>>(asv, adv, row_ptr, colb, pbuf, dnv);
    gat_aggregate3<8, 32, 256, 4, 0, true><<<nbs, 256, 0, stream>>>(
        bufA, pbuf, dnv, row_ptr, colb, b2, bufB);

    // ---- layer 3: 256 -> 128 (1 head, no concat, no elu) ----
    sgemm64<<<g2, 256, 0, stream>>>(bufB, W3, bufA, N_NODES, 256, 128);
    node_alpha3<1, 128><<<nb, 256, 0, stream>>>(bufA, as3, ad3, asv, adv);
    edge_alpha<1><<<nb, 256, 0, stream>>>(asv, adv, row_ptr, colb, pbuf, dnv);
    gat_aggregate3<8, 16, 128, 1, 1, false><<<nbs, 256, 0, stream>>>(
        bufA, pbuf, dnv, row_ptr, colb, b3, hout);

    // ---- global mean pool ----
    pool_mean4<<<dim3(G_GRAPHS, 4), 128, 0, stream>>>(hout, gstart, gout);
}

// Round 3
// 433.233 us; speedup vs baseline: 1.2465x; 1.2465x over previous
//
#include <hip/hip_runtime.h>
#include <hip/hip_bf16.h>
#include <math.h>

#define N_NODES 20000
#define N_EDGES 640000
#define ET_EDGES (N_EDGES + N_NODES)   // with self-loops
#define G_GRAPHS 64
#define NEG_SLOPE 0.2f

typedef __attribute__((ext_vector_type(8))) short s8v;   // 8 bf16 (4 VGPR)
typedef __attribute__((ext_vector_type(4))) float f4v;   // 4 fp32 acc

// fp32 -> bf16 (RNE) and back
__device__ __forceinline__ unsigned short bf_hi(float f) {
    union { float f; unsigned int u; } c; c.f = f;
    unsigned int r = (c.u + 0x7fffu + ((c.u >> 16) & 1u)) >> 16;
    return (unsigned short)r;
}
__device__ __forceinline__ float bf_f(unsigned short h) {
    union { unsigned int u; float f; } c; c.u = ((unsigned int)h) << 16;
    return c.f;
}

// ---------------- CSR construction (+ graph bounds folded in) ----------------

__global__ void hist_dst(const int* __restrict__ ei, int* __restrict__ cnt,
                         const int* __restrict__ batch, int* __restrict__ gstart) {
    int j = blockIdx.x * blockDim.x + threadIdx.x;
    if (blockIdx.x == 0 && threadIdx.x <= G_GRAPHS) {
        int g = threadIdx.x;
        int lo = 0, hi = N_NODES;
        while (lo < hi) {              // first i with batch[i] >= g
            int mid = (lo + hi) >> 1;
            if (batch[mid] < g) lo = mid + 1; else hi = mid;
        }
        gstart[g] = lo;
    }
    if (j >= ET_EDGES) return;
    int d = (j < N_EDGES) ? ei[N_EDGES + j] : (j - N_EDGES);
    atomicAdd(&cnt[d], 1);
}

__global__ __launch_bounds__(1024) void scan_rowptr(const int* __restrict__ cnt,
                                                    int* __restrict__ row_ptr) {
    __shared__ int sums[1024];
    const int n = N_NODES;
    const int CH = (n + 1023) / 1024;   // 20
    int t = threadIdx.x;
    int base = t * CH;
    int s = 0;
    for (int i = 0; i < CH; ++i) {
        int idx = base + i;
        if (idx < n) s += cnt[idx];
    }
    sums[t] = s;
    __syncthreads();
    for (int o = 1; o < 1024; o <<= 1) {
        int v = (t >= o) ? sums[t - o] : 0;
        __syncthreads();
        sums[t] += v;
        __syncthreads();
    }
    int run = (t == 0) ? 0 : sums[t - 1];
    for (int i = 0; i < CH; ++i) {
        int idx = base + i;
        if (idx < n) { row_ptr[idx] = run; run += cnt[idx]; }
    }
    if (t == 1023) row_ptr[n] = sums[1023];
}

__global__ void fill_csr(const int* __restrict__ ei, const int* __restrict__ row_ptr,
                         int* __restrict__ cur, int* __restrict__ col) {
    int j = blockIdx.x * blockDim.x + threadIdx.x;
    if (j >= ET_EDGES) return;
    int s, d;
    if (j < N_EDGES) { s = ei[j]; d = ei[N_EDGES + j]; }
    else             { s = d = j - N_EDGES; }
    int pos = row_ptr[d] + atomicAdd(&cur[d], 1);
    col[pos] = s;
}

// ---------------- fp32 -> (hi,lo) bf16 split helpers ------------------------

// x [n] fp32 -> hi/lo bf16, 4 elems/thread
__global__ void split_f32(const float* __restrict__ in, unsigned short* __restrict__ hi,
                          unsigned short* __restrict__ lo, int n) {
    int i = (blockIdx.x * blockDim.x + threadIdx.x) * 4;
    if (i >= n) return;
    float4 v = *(const float4*)&in[i];
    ushort4 h, l;
    h.x = bf_hi(v.x); l.x = bf_hi(v.x - bf_f(h.x));
    h.y = bf_hi(v.y); l.y = bf_hi(v.y - bf_f(h.y));
    h.z = bf_hi(v.z); l.z = bf_hi(v.z - bf_f(h.z));
    h.w = bf_hi(v.w); l.w = bf_hi(v.w - bf_f(h.w));
    *(ushort4*)&hi[i] = h;
    *(ushort4*)&lo[i] = l;
}

// W [K][N] fp32 -> Wt hi/lo [N][K] bf16 (transpose + split; tiny matrices)
__global__ void wsplit(const float* __restrict__ W, unsigned short* __restrict__ th,
                       unsigned short* __restrict__ tl, int K, int Nc) {
    int idx = blockIdx.x * blockDim.x + threadIdx.x;
    if (idx >= K * Nc) return;
    int k = idx / Nc, n = idx % Nc;
    float v = W[idx];
    unsigned short h = bf_hi(v);
    th[n * K + k] = h;
    tl[n * K + k] = bf_hi(v - bf_f(h));
}

// ---------------- split-bf16 MFMA GEMM: C = A @ B, fp32-accurate ------------
// A given as hi/lo bf16 [M][K]; B given pre-transposed hi/lo bf16 [N][K].
// C = Ah*Bh + Ah*Bl + Al*Bh (lo*lo ~2^-18 rel, dropped). fp32 accumulate.
// Block 256 thr / 4 waves, tile 128x64, wave tile 64x32 (4x2 frags of 16x16),
// mfma_f32_16x16x32_bf16. LDS rows padded to 40 ushorts (80 B) -> 2-way-max
// bank aliasing on ds_read_b128 (free).

#define LDT 40

__global__ __launch_bounds__(256) void gemm_split(
        const unsigned short* __restrict__ Ah, const unsigned short* __restrict__ Al,
        const unsigned short* __restrict__ Bh, const unsigned short* __restrict__ Bl,
        float* __restrict__ C, int M, int Nc, int K) {
    __shared__ unsigned short lAh[128 * LDT];
    __shared__ unsigned short lAl[128 * LDT];
    __shared__ unsigned short lBh[64 * LDT];
    __shared__ unsigned short lBl[64 * LDT];
    int bm = blockIdx.x * 128, bn = blockIdx.y * 64;
    int t = threadIdx.x, w = t >> 6, lane = t & 63;
    int wm = (w >> 1) * 64, wn = (w & 1) * 32;

    f4v acc[4][2] = {};

    // staging coords: A 128x32 -> 16 ushort/thread; B 64x32 -> 8 ushort/thread
    int sr = t >> 1, sk = (t & 1) << 4;     // A: row, k-offset {0,16}
    int br = t >> 2, bk = (t & 3) << 3;     // B: row, k-offset {0,8,16,24}
    int ar = bm + sr; if (ar >= M) ar = M - 1;
    const unsigned short* pAh = Ah + (size_t)ar * K + sk;
    const unsigned short* pAl = Al + (size_t)ar * K + sk;
    const unsigned short* pBh = Bh + (size_t)(bn + br) * K + bk;
    const unsigned short* pBl = Bl + (size_t)(bn + br) * K + bk;

    int fr = lane & 15, fk = (lane >> 4) << 3;

    for (int k0 = 0; k0 < K; k0 += 32) {
        uint4 vh0 = *(const uint4*)(pAh + k0);
        uint4 vh1 = *(const uint4*)(pAh + k0 + 8);
        uint4 vl0 = *(const uint4*)(pAl + k0);
        uint4 vl1 = *(const uint4*)(pAl + k0 + 8);
        uint4 wh  = *(const uint4*)(pBh + k0);
        uint4 wl  = *(const uint4*)(pBl + k0);
        __syncthreads();
        *(uint4*)&lAh[sr * LDT + sk]     = vh0;
        *(uint4*)&lAh[sr * LDT + sk + 8] = vh1;
        *(uint4*)&lAl[sr * LDT + sk]     = vl0;
        *(uint4*)&lAl[sr * LDT + sk + 8] = vl1;
        *(uint4*)&lBh[br * LDT + bk] = wh;
        *(uint4*)&lBl[br * LDT + bk] = wl;
        __syncthreads();

        s8v a_h[4], a_l[4], b_h[2], b_l[2];
        #pragma unroll
        for (int mi = 0; mi < 4; ++mi) {
            a_h[mi] = *(const s8v*)&lAh[(wm + mi * 16 + fr) * LDT + fk];
            a_l[mi] = *(const s8v*)&lAl[(wm + mi * 16 + fr) * LDT + fk];
        }
        #pragma unroll
        for (int nj = 0; nj < 2; ++nj) {
            b_h[nj] = *(const s8v*)&lBh[(wn + nj * 16 + fr) * LDT + fk];
            b_l[nj] = *(const s8v*)&lBl[(wn + nj * 16 + fr) * LDT + fk];
        }
        #pragma unroll
        for (int mi = 0; mi < 4; ++mi)
            #pragma unroll
            for (int nj = 0; nj < 2; ++nj) {
                acc[mi][nj] = __builtin_amdgcn_mfma_f32_16x16x32_bf16(
                    a_h[mi], b_h[nj], acc[mi][nj], 0, 0, 0);
                acc[mi][nj] = __builtin_amdgcn_mfma_f32_16x16x32_bf16(
                    a_h[mi], b_l[nj], acc[mi][nj], 0, 0, 0);
                acc[mi][nj] = __builtin_amdgcn_mfma_f32_16x16x32_bf16(
                    a_l[mi], b_h[nj], acc[mi][nj], 0, 0, 0);
            }
    }

    // C/D layout: col = lane&15, row = (lane>>4)*4 + q  [verified gfx950]
    #pragma unroll
    for (int mi = 0; mi < 4; ++mi)
        #pragma unroll
        for (int nj = 0; nj < 2; ++nj) {
            int row0 = bm + wm + mi * 16 + (lane >> 4) * 4;
            int colc = bn + wn + nj * 16 + (lane & 15);
            #pragma unroll
            for (int q = 0; q < 4; ++q) {
                int r = row0 + q;
                if (r < M) C[(size_t)r * Nc + colc] = acc[mi][nj][q];
            }
        }
}

// ---------------- per-node attention coefficients (transposed out) ---------

template <int HEADS, int C>
__global__ __launch_bounds__(256) void node_alpha2(const float* __restrict__ h,
                                                   const float* __restrict__ a_src,
                                                   const float* __restrict__ a_dst,
                                                   float* __restrict__ asT,   // [HEADS][N]
                                                   float* __restrict__ adT) { // [HEADS][N]
    constexpr int F = HEADS * C;
    constexpr int VEC = F / 64;        // 4 (F=256) or 2 (F=128)
    constexpr int LPH = C / VEC;       // lanes per head: 16 or 64
    int wid = threadIdx.x >> 6, lane = threadIdx.x & 63;
    int v = blockIdx.x * 4 + wid;
    if (v >= N_NODES) return;
    const float* hp = h + (size_t)v * F + lane * VEC;
    float ps = 0.f, pd = 0.f;
    #pragma unroll
    for (int c = 0; c < VEC; ++c) {
        float hv = hp[c];
        ps = fmaf(hv, a_src[lane * VEC + c], ps);
        pd = fmaf(hv, a_dst[lane * VEC + c], pd);
    }
    #pragma unroll
    for (int o = LPH / 2; o; o >>= 1) {
        ps += __shfl_xor(ps, o);
        pd += __shfl_xor(pd, o);
    }
    if ((lane & (LPH - 1)) == 0) {
        int head = lane / LPH;
        asT[head * N_NODES + v] = ps;
        adT[head * N_NODES + v] = pd;
    }
}

// ---------------- channel-sliced softmax-aggregate (R1 design) -------------
// Wave = (dst node, channel slice). NSLICE=4. Edge metadata staged once per
// 64-edge window through LDS; gather loop unrolled x4 for MLP.
// SPLIT=true: write hi/lo bf16 (feeds next layer's MFMA GEMM) instead of f32.

template <int NSLICE, int SCH, int F, int HEADS, bool DO_ELU, bool SPLIT>
__global__ __launch_bounds__(256) void gat_aggregate_sliced(
        const float* __restrict__ h,      // [N, F]
        const float* __restrict__ asT,    // [HEADS][N]
        const float* __restrict__ adT,    // [HEADS][N]
        const int* __restrict__ row_ptr,
        const int* __restrict__ col,
        const float* __restrict__ bias,   // [F]
        float* __restrict__ out,          // [N, F]   (SPLIT=false)
        unsigned short* __restrict__ oh,  // [N, F]   (SPLIT=true)
        unsigned short* __restrict__ ol) {
    constexpr int CL = SCH / 4;           // lanes per edge (16 or 8)
    constexpr int E  = 64 / CL;           // parallel edges (4 or 8)
    constexpr int CPH = F / HEADS;        // channels per head
    __shared__ int   s_off[4][64];
    __shared__ float s_p[4][64];
    int slice = blockIdx.x & (NSLICE - 1);
    int ng = blockIdx.x >> 2;             // NSLICE == 4
    int wid = threadIdx.x >> 6, lane = threadIdx.x & 63;
    int v = ng * 4 + wid;
    if (v >= N_NODES) return;
    int head = (slice * SCH) / CPH;       // layers 1/2: slice == head; layer 3: 0
    int eg = lane / CL, cl = lane % CL;
    int r0 = row_ptr[v], r1 = row_ptr[v + 1];
    float ad = adT[head * N_NODES + v];
    const float* asrc = asT + head * N_NODES;
    float acc[4] = {};
    float lsum = 0.f;
    const char* hb = (const char*)(h + slice * SCH + cl * 4);

#define GATHER4(gg)                                                        \
    {                                                                      \
        int k0 = ((gg) + 0) * E + eg;                                      \
        int k1 = ((gg) + 1) * E + eg;                                      \
        int k2 = ((gg) + 2) * E + eg;                                      \
        int k3 = ((gg) + 3) * E + eg;                                      \
        float p0 = s_p[wid][k0]; int o0 = s_off[wid][k0];                  \
        float p1 = s_p[wid][k1]; int o1 = s_off[wid][k1];                  \
        float p2 = s_p[wid][k2]; int o2 = s_off[wid][k2];                  \
        float p3 = s_p[wid][k3]; int o3 = s_off[wid][k3];                  \
        float4 h0 = *(const float4*)(hb + o0);                             \
        float4 h1 = *(const float4*)(hb + o1);                             \
        float4 h2 = *(const float4*)(hb + o2);                             \
        float4 h3 = *(const float4*)(hb + o3);                             \
        acc[0] = fmaf(p0, h0.x, acc[0]);                                   \
        acc[1] = fmaf(p0, h0.y, acc[1]);                                   \
        acc[2] = fmaf(p0, h0.z, acc[2]);                                   \
        acc[3] = fmaf(p0, h0.w, acc[3]);                                   \
        acc[0] = fmaf(p1, h1.x, acc[0]);                                   \
        acc[1] = fmaf(p1, h1.y, acc[1]);                                   \
        acc[2] = fmaf(p1, h1.z, acc[2]);                                   \
        acc[3] = fmaf(p1, h1.w, acc[3]);                                   \
        acc[0] = fmaf(p2, h2.x, acc[0]);                                   \
        acc[1] = fmaf(p2, h2.y, acc[1]);                                   \
        acc[2] = fmaf(p2, h2.z, acc[2]);                                   \
        acc[3] = fmaf(p2, h2.w, acc[3]);                                   \
        acc[0] = fmaf(p3, h3.x, acc[0]);                                   \
        acc[1] = fmaf(p3, h3.y, acc[1]);                                   \
        acc[2] = fmaf(p3, h3.z, acc[2]);                                   \
        acc[3] = fmaf(p3, h3.w, acc[3]);                                   \
    }

    for (int base = r0; base < r1; base += 64) {
        int j = base + lane;
        bool valid = j < r1;
        int s = col[valid ? j : r0];
        float e = asrc[s] + ad;
        e = (e > 0.f) ? e : NEG_SLOPE * e;
        float p = valid ? __expf(e) : 0.f;
        lsum += p;
        s_p[wid][lane] = p;
        s_off[wid][lane] = s * (F * 4);   // byte offset of row s

        int nk = min(64, r1 - base);
        int nkg = (nk + E - 1) / E;       // <= 64/E
        int g = 0;
        for (; g + 4 <= nkg; g += 4) GATHER4(g);
        if (g < nkg) GATHER4(g);          // ragged tail: extra groups have p==0
    }
#undef GATHER4

    // full-wave softmax denominator
    #pragma unroll
    for (int o = 32; o; o >>= 1) lsum += __shfl_xor(lsum, o);
    // reduce acc across edge groups (lanes differing in bits >= log2(CL))
    #pragma unroll
    for (int c = 0; c < 4; ++c) {
        #pragma unroll
        for (int o = CL; o < 64; o <<= 1) acc[c] += __shfl_xor(acc[c], o);
    }
    if (eg == 0) {
        float inv = 1.f / (lsum + 1e-16f);
        int ch0 = slice * SCH + cl * 4;
        float o4[4];
        #pragma unroll
        for (int c = 0; c < 4; ++c) {
            float o = acc[c] * inv + bias[ch0 + c];
            if (DO_ELU) o = (o > 0.f) ? o : expm1f(o);
            o4[c] = o;
        }
        if (SPLIT) {
            ushort4 hv, lv;
            hv.x = bf_hi(o4[0]); lv.x = bf_hi(o4[0] - bf_f(hv.x));
            hv.y = bf_hi(o4[1]); lv.y = bf_hi(o4[1] - bf_f(hv.y));
            hv.z = bf_hi(o4[2]); lv.z = bf_hi(o4[2] - bf_f(hv.z));
            hv.w = bf_hi(o4[3]); lv.w = bf_hi(o4[3] - bf_f(hv.w));
            *(ushort4*)&oh[(size_t)v * F + ch0] = hv;
            *(ushort4*)&ol[(size_t)v * F + ch0] = lv;
        } else {
            *(float4*)&out[(size_t)v * F + ch0] =
                make_float4(o4[0], o4[1], o4[2], o4[3]);
        }
    }
}

// ---------------- global mean pool: 4-way row-split + atomic combine --------

__global__ void pool_mean4(const float* __restrict__ hout, const int* __restrict__ gstart,
                           float* __restrict__ gout) {
    int g = blockIdx.x;       // 64
    int q = blockIdx.y;       // 4 row-quarters
    int c = threadIdx.x;      // 128 channels
    int off = gstart[g], end = gstart[g + 1];
    float inv = 1.f / fmaxf((float)(end - off), 1.0f);
    float s = 0.f;
    for (int i = off + q; i < end; i += 4) s += hout[(size_t)i * 128 + c];
    atomicAdd(&gout[g * 128 + c], s * inv);
}

// ---------------- launch ----------------

static inline size_t align_up(size_t x, size_t a) { return (x + a - 1) & ~(a - 1); }

extern "C" void kernel_launch(void* const* d_in, const int* in_sizes, int n_in,
                              void* d_out, int out_size, void* d_ws, size_t ws_size,
                              hipStream_t stream) {
    const float* x   = (const float*)d_in[0];
    const int*   ei  = (const int*)d_in[1];
    const int*   bat = (const int*)d_in[2];
    const float* W1  = (const float*)d_in[3];
    const float* as1 = (const float*)d_in[4];
    const float* ad1 = (const float*)d_in[5];
    const float* b1  = (const float*)d_in[6];
    const float* W2  = (const float*)d_in[7];
    const float* as2 = (const float*)d_in[8];
    const float* ad2 = (const float*)d_in[9];
    const float* b2  = (const float*)d_in[10];
    const float* W3  = (const float*)d_in[11];
    const float* as3 = (const float*)d_in[12];
    const float* ad3 = (const float*)d_in[13];
    const float* b3  = (const float*)d_in[14];

    float* gout = (float*)d_out;                     // [G,128]
    float* hout = (float*)d_out + G_GRAPHS * 128;    // [N,128]

    char* w = (char*)d_ws;
    size_t o = 0;
    float* bufA = (float*)(w + o);           o = align_up(o + (size_t)N_NODES * 256 * 4, 256);
    unsigned short* Bh = (unsigned short*)(w + o); o = align_up(o + (size_t)N_NODES * 256 * 2, 256);
    unsigned short* Bl = (unsigned short*)(w + o); o = align_up(o + (size_t)N_NODES * 256 * 2, 256);
    unsigned short* xh = (unsigned short*)(w + o); o = align_up(o + (size_t)N_NODES * 128 * 2, 256);
    unsigned short* xl = (unsigned short*)(w + o); o = align_up(o + (size_t)N_NODES * 128 * 2, 256);
    unsigned short* Wt1h = (unsigned short*)(w + o); o = align_up(o + (size_t)256 * 128 * 2, 256);
    unsigned short* Wt1l = (unsigned short*)(w + o); o = align_up(o + (size_t)256 * 128 * 2, 256);
    unsigned short* Wt2h = (unsigned short*)(w + o); o = align_up(o + (size_t)256 * 256 * 2, 256);
    unsigned short* Wt2l = (unsigned short*)(w + o); o = align_up(o + (size_t)256 * 256 * 2, 256);
    unsigned short* Wt3h = (unsigned short*)(w + o); o = align_up(o + (size_t)128 * 256 * 2, 256);
    unsigned short* Wt3l = (unsigned short*)(w + o); o = align_up(o + (size_t)128 * 256 * 2, 256);
    float* asv  = (float*)(w + o); o = align_up(o + (size_t)N_NODES * 4 * 4, 256);
    float* adv  = (float*)(w + o); o = align_up(o + (size_t)N_NODES * 4 * 4, 256);
    int* row_ptr = (int*)(w + o);  o = align_up(o + (size_t)(N_NODES + 1) * 4, 256);
    int* col     = (int*)(w + o);  o = align_up(o + (size_t)ET_EDGES * 4, 256);
    int* cnt     = (int*)(w + o);  o += (size_t)N_NODES * 4;        // cnt+cur contiguous
    int* cur     = (int*)(w + o);  o = align_up(o + (size_t)N_NODES * 4, 256);
    int* gstart  = (int*)(w + o);  o = align_up(o + (size_t)(G_GRAPHS + 1) * 4, 256);

    // ---- CSR build + graph bounds + weight/input splits ----
    hipMemsetAsync(cnt, 0, (size_t)N_NODES * 8, stream);   // cnt AND cur
    hipMemsetAsync(gout, 0, (size_t)G_GRAPHS * 128 * 4, stream);
    hist_dst<<<(ET_EDGES + 255) / 256, 256, 0, stream>>>(ei, cnt, bat, gstart);
    scan_rowptr<<<1, 1024, 0, stream>>>(cnt, row_ptr);
    fill_csr<<<(ET_EDGES + 255) / 256, 256, 0, stream>>>(ei, row_ptr, cur, col);
    split_f32<<<(N_NODES * 128 / 4 + 255) / 256, 256, 0, stream>>>(x, xh, xl, N_NODES * 128);
    wsplit<<<(128 * 256 + 255) / 256, 256, 0, stream>>>(W1, Wt1h, Wt1l, 128, 256);
    wsplit<<<(256 * 256 + 255) / 256, 256, 0, stream>>>(W2, Wt2h, Wt2l, 256, 256);
    wsplit<<<(256 * 128 + 255) / 256, 256, 0, stream>>>(W3, Wt3h, Wt3l, 256, 128);

    int gm = (N_NODES + 127) / 128;   // 157
    int nb = (N_NODES + 3) / 4;       // 4 nodes per block
    int nbs = nb * 4;                 // x4 channel slices

    // ---- layer 1: 128 -> 4x64 ----
    gemm_split<<<dim3(gm, 4), 256, 0, stream>>>(xh, xl, Wt1h, Wt1l, bufA, N_NODES, 256, 128);
    node_alpha2<4, 64><<<nb, 256, 0, stream>>>(bufA, as1, ad1, asv, adv);
    gat_aggregate_sliced<4, 64, 256, 4, true, true><<<nbs, 256, 0, stream>>>(
        bufA, asv, adv, row_ptr, col, b1, nullptr, Bh, Bl);

    // ---- layer 2: 256 -> 4x64 ----
    gemm_split<<<dim3(gm, 4), 256, 0, stream>>>(Bh, Bl, Wt2h, Wt2l, bufA, N_NODES, 256, 256);
    node_alpha2<4, 64><<<nb, 256, 0, stream>>>(bufA, as2, ad2, asv, adv);
    gat_aggregate_sliced<4, 64, 256, 4, true, true><<<nbs, 256, 0, stream>>>(
        bufA, asv, adv, row_ptr, col, b2, nullptr, Bh, Bl);

    // ---- layer 3: 256 -> 128 (1 head, no concat, no elu) ----
    gemm_split<<<dim3(gm, 2), 256, 0, stream>>>(Bh, Bl, Wt3h, Wt3l, bufA, N_NODES, 128, 256);
    node_alpha2<1, 128><<<nb, 256, 0, stream>>>(bufA, as3, ad3, asv, adv);
    gat_aggregate_sliced<4, 32, 128, 1, false, false><<<nbs, 256, 0, stream>>>(
        bufA, asv, adv, row_ptr, col, b3, hout, nullptr, nullptr);

    // ---- global mean pool ----
    pool_mean4<<<dim3(G_GRAPHS, 4), 128, 0, stream>>>(hout, gstart, gout);
}